// Round 5
// baseline (3802.682 us; speedup 1.0000x reference)
//
#include <hip/hip_runtime.h>

#define NEMB 1024
#define CDIM 256
#define NPOS 131072            // 32*64*64 positions
#define Z_ELEMS 33554432       // 32*256*64*64

// d_out is FLOAT32 (reference outputs fp32/int32 -> "else float*").
// Flat layout [z_q | cl | cml | indices] verified by round-0 evidence;
// the checker compares vs bf16-rounded np ref with threshold 2%*1024.
#define SC_OFF  ((size_t)33554432)
#define IDX_OFF ((size_t)33554434)

// Bitwise replication of numpy pairwise_sum of a[i]^2 over 256 contiguous
// floats: n=256 -> split 128+128; each 128-block uses 8 stride-8 accumulators
// combined ((r0+r1)+(r2+r3))+((r4+r5)+(r6+r7)). Squares are materialized
// (rounded) separately -> FP contraction OFF.
__device__ __forceinline__ float np_pairwise_sq256(const float* a) {
#pragma clang fp contract(off)
  float s0, s1;
  {
    float r[8];
#pragma unroll
    for (int j = 0; j < 8; ++j) { float v = a[j]; r[j] = v * v; }
#pragma unroll
    for (int i = 8; i < 128; i += 8) {
#pragma unroll
      for (int j = 0; j < 8; ++j) { float v = a[i + j]; r[j] += v * v; }
    }
    s0 = ((r[0] + r[1]) + (r[2] + r[3])) + ((r[4] + r[5]) + (r[6] + r[7]));
  }
  {
    float r[8];
#pragma unroll
    for (int j = 0; j < 8; ++j) { float v = a[128 + j]; r[j] = v * v; }
#pragma unroll
    for (int i = 8; i < 128; i += 8) {
#pragma unroll
      for (int j = 0; j < 8; ++j) { float v = a[128 + i + j]; r[j] += v * v; }
    }
    s1 = ((r[0] + r[1]) + (r[2] + r[3])) + ((r[4] + r[5]) + (r[6] + r[7]));
  }
  return s0 + s1;
}

// Bsq[k] = numpy-pairwise sum of codebook[k][:]^2 ; also zero the loss acc.
__global__ void vq_bsq(const float* __restrict__ cb, float* __restrict__ Bsq,
                       double* __restrict__ loss_acc) {
  int k = blockIdx.x * blockDim.x + threadIdx.x;
  if (k == 0) *loss_acc = 0.0;
  if (k < NEMB) Bsq[k] = np_pairwise_sq256(cb + (size_t)k * CDIM);
}

__global__ __launch_bounds__(256) void vq_main(
    const float* __restrict__ z, const float* __restrict__ cb,
    const float* __restrict__ Bsq, float* __restrict__ out,
    double* __restrict__ loss_acc) {
  __shared__ float zt[64][257];   // [w][c], +1 pad -> conflict-free
  __shared__ float Bs[NEMB];
  __shared__ float Aw[64];
  __shared__ float dmin_s[4][64];
  __shared__ int kmin_s[4][64];
  __shared__ int idx_s[64];
  __shared__ double wsum[4];

  const int tid = threadIdx.x;
  const int bh = blockIdx.x;              // b*64 + h
  const int b = bh >> 6, h = bh & 63;
  const size_t zbase = (size_t)b * CDIM * 4096 + (size_t)h * 64;  // + c*4096 + w

  // stage z tile (coalesced: consecutive w per channel row)
  for (int i = tid; i < CDIM * 64; i += 256) {
    int c = i >> 6, w = i & 63;
    zt[w][c] = z[zbase + (size_t)c * 4096 + w];
  }
  for (int i = tid; i < NEMB; i += 256) Bs[i] = Bsq[i];
  __syncthreads();

  // A_n per position: bitwise numpy-pairwise fp32
  if (tid < 64) Aw[tid] = np_pairwise_sq256(&zt[tid][0]);
  __syncthreads();

  const int wv = tid >> 6;                 // wave 0..3 -> k-chunk
  const int lane = tid & 63;               // position w
  const int k0 = wv * 256;
  const float A = Aw[lane];
  const float* zrow = &zt[lane][0];

  // BLAS-faithful C: one accumulator per code, sequential FMA over ascending
  // c (sgemm microkernels are rank-1 update chains per C element).
  float dmin = INFINITY;
  int kmin = 0;
  for (int kb = k0; kb < k0 + 256; kb += 16) {
    const float* cbase = cb + (size_t)kb * CDIM;  // wave-uniform -> s_loads
    float acc[16];
#pragma unroll
    for (int j = 0; j < 16; ++j) acc[j] = 0.0f;
    for (int c = 0; c < CDIM; c += 4) {
      float z0 = zrow[c], z1 = zrow[c + 1], z2 = zrow[c + 2], z3 = zrow[c + 3];
#pragma unroll
      for (int j = 0; j < 16; ++j) {
        const float* cr = cbase + j * CDIM + c;
        float a = acc[j];
        a = __builtin_fmaf(z0, cr[0], a);
        a = __builtin_fmaf(z1, cr[1], a);
        a = __builtin_fmaf(z2, cr[2], a);
        a = __builtin_fmaf(z3, cr[3], a);
        acc[j] = a;
      }
    }
#pragma unroll
    for (int j = 0; j < 16; ++j) {
      // np chain: fl( fl(A+B) - 2*C ); 2*C exact, fma-contraction-safe
      float d = (A + Bs[kb + j]) - 2.0f * acc[j];
      if (d < dmin) { dmin = d; kmin = kb + j; }  // strict < : first-index ties
    }
  }
  dmin_s[wv][lane] = dmin;
  kmin_s[wv][lane] = kmin;
  __syncthreads();

  if (tid < 64) {
    float dm = dmin_s[0][tid];
    int km = kmin_s[0][tid];
#pragma unroll
    for (int v = 1; v < 4; ++v) {   // ascending k-chunks keep np tie order
      float dv = dmin_s[v][tid];
      int kv = kmin_s[v][tid];
      if (dv < dm) { dm = dv; km = kv; }
    }
    idx_s[tid] = km;
    out[IDX_OFF + (size_t)bh * 64 + tid] = (float)km;   // fp32 index
  }
  __syncthreads();

  // z_q = fl(z + fl(e - z)) fp32; loss = sum (e-z)^2
  double lsum = 0.0;
  for (int i = tid; i < CDIM * 64; i += 256) {
    int c = i >> 6, w = i & 63;
    float e = cb[(size_t)idx_s[w] * CDIM + c];
    float zz = zt[w][c];
    float diff = e - zz;
    lsum += (double)diff * (double)diff;
    out[zbase + (size_t)c * 4096 + w] = zz + diff;
  }
  for (int off = 32; off; off >>= 1) lsum += __shfl_down(lsum, off);
  if (lane == 0) wsum[wv] = lsum;
  __syncthreads();
  if (tid == 0) atomicAdd(loss_acc, wsum[0] + wsum[1] + wsum[2] + wsum[3]);
}

__global__ void vq_finalize(const double* __restrict__ loss_acc,
                            float* __restrict__ out) {
  double m = *loss_acc / (double)Z_ELEMS;
  out[SC_OFF] = (float)m;
  out[SC_OFF + 1] = (float)(0.25 * m);
}

extern "C" void kernel_launch(void* const* d_in, const int* in_sizes, int n_in,
                              void* d_out, int out_size, void* d_ws,
                              size_t ws_size, hipStream_t stream) {
  (void)n_in; (void)ws_size; (void)out_size;
  // in_sizes verified element counts; dict order verified correct.
  const float* z;
  const float* cb;
  if (in_sizes[0] == Z_ELEMS) {
    z = (const float*)d_in[0];
    cb = (const float*)d_in[1];
  } else {
    z = (const float*)d_in[1];
    cb = (const float*)d_in[0];
  }
  float* out = (float*)d_out;
  double* loss = (double*)d_ws;                 // 8 bytes
  float* Bsq = (float*)((char*)d_ws + 256);     // 4 KB

  vq_bsq<<<dim3(16), dim3(64), 0, stream>>>(cb, Bsq, loss);
  vq_main<<<dim3(2048), dim3(256), 0, stream>>>(z, cb, Bsq, out, loss);
  vq_finalize<<<dim3(1), dim3(1), 0, stream>>>(loss, out);
}

// Round 6
// 1871.837 us; speedup vs baseline: 2.0315x; 2.0315x over previous
//
#include <hip/hip_runtime.h>

#define NEMB 1024
#define CDIM 256
#define NPOS 131072            // 32*64*64 positions
#define Z_ELEMS 33554432       // 32*256*64*64

// d_out is FLOAT32, flat layout [z_q | cl | cml | indices] (verified r0/r5).
#define SC_OFF  ((size_t)33554432)
#define IDX_OFF ((size_t)33554434)

// Bitwise replication of numpy pairwise_sum of a[i]^2 over 256 contiguous
// floats: n=256 -> split 128+128; each 128-block uses 8 stride-8 accumulators
// combined ((r0+r1)+(r2+r3))+((r4+r5)+(r6+r7)). Squares are materialized
// (rounded) separately -> FP contraction OFF.
__device__ __forceinline__ float np_pairwise_sq256(const float* a) {
#pragma clang fp contract(off)
  float s0, s1;
  {
    float r[8];
#pragma unroll
    for (int j = 0; j < 8; ++j) { float v = a[j]; r[j] = v * v; }
#pragma unroll
    for (int i = 8; i < 128; i += 8) {
#pragma unroll
      for (int j = 0; j < 8; ++j) { float v = a[i + j]; r[j] += v * v; }
    }
    s0 = ((r[0] + r[1]) + (r[2] + r[3])) + ((r[4] + r[5]) + (r[6] + r[7]));
  }
  {
    float r[8];
#pragma unroll
    for (int j = 0; j < 8; ++j) { float v = a[128 + j]; r[j] = v * v; }
#pragma unroll
    for (int i = 8; i < 128; i += 8) {
#pragma unroll
      for (int j = 0; j < 8; ++j) { float v = a[128 + i + j]; r[j] += v * v; }
    }
    s1 = ((r[0] + r[1]) + (r[2] + r[3])) + ((r[4] + r[5]) + (r[6] + r[7]));
  }
  return s0 + s1;
}

__global__ void vq_bsq(const float* __restrict__ cb, float* __restrict__ Bsq,
                       double* __restrict__ loss_acc) {
  int k = blockIdx.x * blockDim.x + threadIdx.x;
  if (k == 0) *loss_acc = 0.0;
  if (k < NEMB) Bsq[k] = np_pairwise_sq256(cb + (size_t)k * CDIM);
}

__global__ __launch_bounds__(256) void vq_main(
    const float* __restrict__ z, const float* __restrict__ cb,
    const float* __restrict__ Bsq, float* __restrict__ out,
    double* __restrict__ loss_acc) {
  __shared__ float zt[64][257];   // [w][c], +1 pad -> conflict-free
  __shared__ float Bs[NEMB];
  __shared__ float Aw[64];
  __shared__ float dmin_s[4][64];
  __shared__ int kmin_s[4][64];
  __shared__ int idx_s[64];
  __shared__ double wsum[4];

  const int tid = threadIdx.x;
  const int bh = blockIdx.x;              // b*64 + h
  const int b = bh >> 6, h = bh & 63;
  const size_t zbase = (size_t)b * CDIM * 4096 + (size_t)h * 64;  // + c*4096 + w

  for (int i = tid; i < CDIM * 64; i += 256) {
    int c = i >> 6, w = i & 63;
    zt[w][c] = z[zbase + (size_t)c * 4096 + w];
  }
  for (int i = tid; i < NEMB; i += 256) Bs[i] = Bsq[i];
  __syncthreads();

  if (tid < 64) Aw[tid] = np_pairwise_sq256(&zt[tid][0]);
  __syncthreads();

  // readfirstlane: PROVE wave-uniformity of the k-chunk to the compiler so
  // codebook accesses become s_load_dwordx4 (+imm offset) feeding
  // v_fmac_f32 with an SGPR operand — r5 showed that without this, LLVM's
  // divergence analysis emits per-lane global_loads + 64-bit vector address
  // math (VALUBusy 34%, FMA only ~11% of issue slots).
  const int wv = __builtin_amdgcn_readfirstlane(tid >> 6);  // wave 0..3
  const int lane = tid & 63;               // position w
  const int k0 = wv * 256;
  const float A = Aw[lane];
  const float* zrow = &zt[lane][0];

  // BLAS-faithful C: one accumulator per code, sequential FMA over ascending
  // c (sgemm microkernels are rank-1 update chains per C element).
  float dmin = INFINITY;
  int kmin = 0;
  for (int kb = k0; kb < k0 + 256; kb += 16) {
    const float* cbase = cb + (size_t)kb * CDIM;  // wave-uniform -> s_loads
    float acc[16];
#pragma unroll
    for (int j = 0; j < 16; ++j) acc[j] = 0.0f;
    for (int c = 0; c < CDIM; c += 4) {
      float z0 = zrow[c], z1 = zrow[c + 1], z2 = zrow[c + 2], z3 = zrow[c + 3];
#pragma unroll
      for (int j = 0; j < 16; ++j) {
        const float* cr = cbase + j * CDIM + c;
        float a = acc[j];
        a = __builtin_fmaf(z0, cr[0], a);
        a = __builtin_fmaf(z1, cr[1], a);
        a = __builtin_fmaf(z2, cr[2], a);
        a = __builtin_fmaf(z3, cr[3], a);
        acc[j] = a;
      }
    }
#pragma unroll
    for (int j = 0; j < 16; ++j) {
      // np chain: fl( fl(A+B) - 2*C ); 2*C exact, fma-contraction-safe
      float d = (A + Bs[kb + j]) - 2.0f * acc[j];
      if (d < dmin) { dmin = d; kmin = kb + j; }  // strict < : first-index ties
    }
  }
  dmin_s[wv][lane] = dmin;
  kmin_s[wv][lane] = kmin;
  __syncthreads();

  if (tid < 64) {
    float dm = dmin_s[0][tid];
    int km = kmin_s[0][tid];
#pragma unroll
    for (int v = 1; v < 4; ++v) {   // ascending k-chunks keep np tie order
      float dv = dmin_s[v][tid];
      int kv = kmin_s[v][tid];
      if (dv < dm) { dm = dv; km = kv; }
    }
    idx_s[tid] = km;
    out[IDX_OFF + (size_t)bh * 64 + tid] = (float)km;   // fp32 index
  }
  __syncthreads();

  // z_q = fl(z + fl(e - z)) fp32; loss = sum (e-z)^2
  double lsum = 0.0;
  for (int i = tid; i < CDIM * 64; i += 256) {
    int c = i >> 6, w = i & 63;
    float e = cb[(size_t)idx_s[w] * CDIM + c];
    float zz = zt[w][c];
    float diff = e - zz;
    lsum += (double)diff * (double)diff;
    out[zbase + (size_t)c * 4096 + w] = zz + diff;
  }
  for (int off = 32; off; off >>= 1) lsum += __shfl_down(lsum, off);
  if (lane == 0) wsum[wv] = lsum;
  __syncthreads();
  if (tid == 0) atomicAdd(loss_acc, wsum[0] + wsum[1] + wsum[2] + wsum[3]);
}

__global__ void vq_finalize(const double* __restrict__ loss_acc,
                            float* __restrict__ out) {
  double m = *loss_acc / (double)Z_ELEMS;
  out[SC_OFF] = (float)m;
  out[SC_OFF + 1] = (float)(0.25 * m);
}

extern "C" void kernel_launch(void* const* d_in, const int* in_sizes, int n_in,
                              void* d_out, int out_size, void* d_ws,
                              size_t ws_size, hipStream_t stream) {
  (void)n_in; (void)ws_size; (void)out_size;
  const float* z;
  const float* cb;
  if (in_sizes[0] == Z_ELEMS) {
    z = (const float*)d_in[0];
    cb = (const float*)d_in[1];
  } else {
    z = (const float*)d_in[1];
    cb = (const float*)d_in[0];
  }
  float* out = (float*)d_out;
  double* loss = (double*)d_ws;                 // 8 bytes
  float* Bsq = (float*)((char*)d_ws + 256);     // 4 KB

  vq_bsq<<<dim3(16), dim3(64), 0, stream>>>(cb, Bsq, loss);
  vq_main<<<dim3(2048), dim3(256), 0, stream>>>(z, cb, Bsq, out, loss);
  vq_finalize<<<dim3(1), dim3(1), 0, stream>>>(loss, out);
}